// Round 7
// baseline (174.032 us; speedup 1.0000x reference)
//
#include <hip/hip_runtime.h>
#include <math.h>

// Problem constants (B=8, H=8, N=2048, C=64). fp32 inputs/outputs.
// Q staged in d_ws as bf16 PRE-SCALED by C^-0.5 * log2(e) (flash uses exp2 =
// bare v_exp_f32). K natural [head][n][c]; V transposed Vt[head][c][n].
// Round 15: revert to round-12/R4 base (passed twice, 164.5 us). TK=64
// DROPPED (deterministic mis-compute in R5/R6, identical absmax — algebra
// audits inconclusive, mechanism abandoned). Single change this round:
// flash TQ=128 / grid 1024 (tm=1): 4 blocks/CU (was grid-capped at 2),
// LDS 24 KB/block, same verified swizzles/staging. Proj = R4 verbatim.
#define BH    64
#define NSEQ  2048
#define CDIM  64
#define WSTR  72   // proj Wb row stride in u16

typedef unsigned short ushort_t;
typedef __attribute__((ext_vector_type(8))) short short8;    // 8 bf16 (4 VGPR)
typedef __attribute__((ext_vector_type(4))) float float4v;   // mfma C/D

// fp32 -> bf16 bits, round-to-nearest-even
__device__ __forceinline__ ushort_t f32_to_bf16_rne(float x) {
  unsigned int u = __float_as_uint(x);
  u += 0x7fffu + ((u >> 16) & 1u);
  return (ushort_t)(u >> 16);
}

// pack 2 f32 -> 2 bf16 in a u32, single HW instruction (RNE)
__device__ __forceinline__ unsigned int cvtpk(float a, float b) {
  unsigned int r;
  asm("v_cvt_pk_bf16_f32 %0, %1, %2" : "=v"(r) : "v"(a), "v"(b));
  return r;
}

// async global->LDS, 16B per lane; LDS dest = wave-uniform base + lane*16
__device__ __forceinline__ void glds16(const ushort_t* g, ushort_t* l) {
  __builtin_amdgcn_global_load_lds(
      (const __attribute__((address_space(1))) void*)g,
      (__attribute__((address_space(3))) void*)l, 16, 0, 0);
}

// ---------------- QKV projection (MFMA, LDS-gathered coalesced stores) ----
// qkv[row, d] = sum_c x[row, c] * W[d, c];  d<64 -> Q (x 0.125*log2e), <128 ->
// K, else V.  Q/K: acc = mfma(wf, xf) -> D[d][row]; V: acc = mfma(xf, wf) ->
// D[row][c] (free transpose for Vt).  Epilogue: pack accs into swizzled LDS
// (overlaid on Wb), read back linearly, store coalesced uint4.
__global__ __launch_bounds__(256) void qkv_proj_mfma(
    const float* __restrict__ x, const float* __restrict__ w,
    ushort_t* __restrict__ q, ushort_t* __restrict__ k,
    ushort_t* __restrict__ vt) {
  __shared__ ushort_t Wb[192 * WSTR];   // 27648 B; reused as gather buffer
  ushort_t* Sg = Wb;                    // overlay (16384 B needed)
  const int t = threadIdx.x;
  const int lane = t & 63, wv = t >> 6;
  const int quad = lane >> 4, l16 = lane & 15;
  const long rowbase = (long)blockIdx.x * 128;
  const int head  = (int)(rowbase >> 11);
  const int nbase = (int)(rowbase & 2047);

  // stage W as bf16; Q-rows (d<64) pre-scaled by 0.125*log2(e)
  for (int u = t; u < 1536; u += 256) {
    const int d = u >> 3, o8 = (u & 7) * 8;
    const float sc = (d < 64) ? 0.1803368801111244f : 1.0f;  // 0.125*log2(e)
    const float4 f0 = *reinterpret_cast<const float4*>(w + d * 64 + o8);
    const float4 f1 = *reinterpret_cast<const float4*>(w + d * 64 + o8 + 4);
    ushort_t tmp[8] __attribute__((aligned(16)));
    tmp[0] = f32_to_bf16_rne(f0.x * sc); tmp[1] = f32_to_bf16_rne(f0.y * sc);
    tmp[2] = f32_to_bf16_rne(f0.z * sc); tmp[3] = f32_to_bf16_rne(f0.w * sc);
    tmp[4] = f32_to_bf16_rne(f1.x * sc); tmp[5] = f32_to_bf16_rne(f1.y * sc);
    tmp[6] = f32_to_bf16_rne(f1.z * sc); tmp[7] = f32_to_bf16_rne(f1.w * sc);
    *reinterpret_cast<uint4*>(&Wb[d * WSTR + o8]) = *reinterpret_cast<const uint4*>(tmp);
  }
  __syncthreads();

  // A/B x-frags: x rows, converted to bf16
  short8 xf[2][2];
#pragma unroll
  for (int tm = 0; tm < 2; ++tm)
#pragma unroll
    for (int kb = 0; kb < 2; ++kb) {
      const float* xp = x + (rowbase + wv * 32 + tm * 16 + l16) * 64 + kb * 32 + quad * 8;
      const float4 f0 = *reinterpret_cast<const float4*>(xp);
      const float4 f1 = *reinterpret_cast<const float4*>(xp + 4);
      ushort_t tmp[8] __attribute__((aligned(16)));
      tmp[0] = f32_to_bf16_rne(f0.x); tmp[1] = f32_to_bf16_rne(f0.y);
      tmp[2] = f32_to_bf16_rne(f0.z); tmp[3] = f32_to_bf16_rne(f0.w);
      tmp[4] = f32_to_bf16_rne(f1.x); tmp[5] = f32_to_bf16_rne(f1.y);
      tmp[6] = f32_to_bf16_rne(f1.z); tmp[7] = f32_to_bf16_rne(f1.w);
      xf[tm][kb] = *reinterpret_cast<const short8*>(tmp);
    }

  float4v aqk[8][2];   // [d-tile][x-tile], swapped: D[d][row]
  float4v av[2][4];    // [x-tile][d-tile], normal: D[row][c]
#pragma unroll
  for (int nt = 0; nt < 8; ++nt)
#pragma unroll
    for (int tm = 0; tm < 2; ++tm)
#pragma unroll
      for (int r = 0; r < 4; ++r) aqk[nt][tm][r] = 0.f;
#pragma unroll
  for (int tm = 0; tm < 2; ++tm)
#pragma unroll
    for (int nt = 0; nt < 4; ++nt)
#pragma unroll
      for (int r = 0; r < 4; ++r) av[tm][nt][r] = 0.f;

#pragma unroll
  for (int kb = 0; kb < 2; ++kb) {
#pragma unroll
    for (int nt = 0; nt < 8; ++nt) {
      const short8 wf = *reinterpret_cast<const short8*>(
          &Wb[(nt * 16 + l16) * WSTR + kb * 32 + quad * 8]);
      aqk[nt][0] = __builtin_amdgcn_mfma_f32_16x16x32_bf16(wf, xf[0][kb], aqk[nt][0], 0, 0, 0);
      aqk[nt][1] = __builtin_amdgcn_mfma_f32_16x16x32_bf16(wf, xf[1][kb], aqk[nt][1], 0, 0, 0);
    }
#pragma unroll
    for (int nt = 0; nt < 4; ++nt) {
      const short8 wfv = *reinterpret_cast<const short8*>(
          &Wb[((128 + nt * 16) + l16) * WSTR + kb * 32 + quad * 8]);
      av[0][nt] = __builtin_amdgcn_mfma_f32_16x16x32_bf16(xf[0][kb], wfv, av[0][nt], 0, 0, 0);
      av[1][nt] = __builtin_amdgcn_mfma_f32_16x16x32_bf16(xf[1][kb], wfv, av[1][nt], 0, 0, 0);
    }
  }

  __syncthreads();   // all MFMA reads of Wb done -> safe to reuse as Sg

  // ---- Q section: gather into Sg[row][d] (chunk ^= row&7), store coalesced
#pragma unroll
  for (int tm = 0; tm < 2; ++tm) {
    const int row = wv * 32 + tm * 16 + l16;
#pragma unroll
    for (int nt = 0; nt < 4; ++nt) {
      const int dchunk = nt * 2 + (quad >> 1);
      uint2 pk;
      pk.x = cvtpk(aqk[nt][tm][0], aqk[nt][tm][1]);
      pk.y = cvtpk(aqk[nt][tm][2], aqk[nt][tm][3]);
      *reinterpret_cast<uint2*>(
          &Sg[row * 64 + ((dchunk ^ (row & 7)) * 8) + (quad & 1) * 4]) = pk;
    }
  }
  __syncthreads();
#pragma unroll
  for (int i = 0; i < 4; ++i) {
    const int g = i * 256 + t;           // 1024 chunks = 128 rows x 8
    const int row = g >> 3, ch = g & 7;
    const uint4 v = *reinterpret_cast<const uint4*>(
        &Sg[row * 64 + ((ch ^ (row & 7)) * 8)]);
    *reinterpret_cast<uint4*>(q + (rowbase + row) * 64 + ch * 8) = v;
  }
  __syncthreads();

  // ---- K section (reuse Sg)
#pragma unroll
  for (int tm = 0; tm < 2; ++tm) {
    const int row = wv * 32 + tm * 16 + l16;
#pragma unroll
    for (int nt = 4; nt < 8; ++nt) {
      const int dchunk = (nt - 4) * 2 + (quad >> 1);
      uint2 pk;
      pk.x = cvtpk(aqk[nt][tm][0], aqk[nt][tm][1]);
      pk.y = cvtpk(aqk[nt][tm][2], aqk[nt][tm][3]);
      *reinterpret_cast<uint2*>(
          &Sg[row * 64 + ((dchunk ^ (row & 7)) * 8) + (quad & 1) * 4]) = pk;
    }
  }
  __syncthreads();
#pragma unroll
  for (int i = 0; i < 4; ++i) {
    const int g = i * 256 + t;
    const int row = g >> 3, ch = g & 7;
    const uint4 v = *reinterpret_cast<const uint4*>(
        &Sg[row * 64 + ((ch ^ (row & 7)) * 8)]);
    *reinterpret_cast<uint4*>(k + (rowbase + row) * 64 + ch * 8) = v;
  }
  __syncthreads();

  // ---- V section: Sg as [64][128] (Sv[c][n_local], chunk ^= c&15)
#pragma unroll
  for (int tm = 0; tm < 2; ++tm)
#pragma unroll
    for (int nt = 0; nt < 4; ++nt) {
      const int c = nt * 16 + l16;
      const int nchunk = wv * 4 + tm * 2 + (quad >> 1);
      uint2 pk;
      pk.x = cvtpk(av[tm][nt][0], av[tm][nt][1]);
      pk.y = cvtpk(av[tm][nt][2], av[tm][nt][3]);
      *reinterpret_cast<uint2*>(
          &Sg[c * 128 + ((nchunk ^ (c & 15)) * 8) + (quad & 1) * 4]) = pk;
    }
  __syncthreads();
#pragma unroll
  for (int i = 0; i < 4; ++i) {
    const int g = i * 256 + t;           // 1024 chunks = 64 c-rows x 16
    const int c = g >> 4, ch = g & 15;
    const uint4 v = *reinterpret_cast<const uint4*>(
        &Sg[c * 128 + ((ch ^ (c & 15)) * 8)]);
    *reinterpret_cast<uint4*>(vt + (long)head * (64 * 2048) + (long)c * 2048 +
                              nbase + ch * 8) = v;
  }
}

// ---------------- MFMA flash attention (transposed dataflow, TQ=128) --------
// block: 512 threads = 8 waves, 16 q-rows per wave (tm=1). TK=32. grid 1024
// (4 blocks/CU -> up to 32 waves/CU; was grid-capped at 16). XCD swizzle:
// bh = ((id&7)<<3)|((id>>3)&7), qt = id>>6 in 0..15.
// LDS (all XOR-swizzled, chunk = 8 u16 = 16B):
//   Ks2[2][32*64]: K tile [kv][c],  chunk' = chunk ^ (row&7)      (8 chunks/row)
//   Vs2[2][64*32]: Vt tile [c][kv], chunk' = chunk ^ ((row>>1)&3) (4 chunks/row)
//   Ps  [128*32]:  P [qrow][kv],    chunk' = chunk ^ ((row>>1)&3)
// Staging split: waves 0-3 stage K (8 rows each), waves 4-7 stage Vt
// (16 c-rows each) -- one glds16 per thread per tile. (Verbatim R4 staging.)
// S^T = mfma(kf, qf): reg r = S[qrow=l16][kv=nt*16+quad*4+r] -> b64 pack.
// O^T = mfma(vf, pf): reg r = O[qrow=l16][c=ct*16+quad*4+r] -> float4 out.
__global__ __launch_bounds__(512, 4) void flash_attn_mfma(
    const ushort_t* __restrict__ q, const ushort_t* __restrict__ k,
    const ushort_t* __restrict__ vt, float* __restrict__ out) {
  __shared__ ushort_t Ks2[2][32 * 64];  // 8 KB
  __shared__ ushort_t Vs2[2][64 * 32];  // 8 KB
  __shared__ ushort_t Ps[128 * 32];     // 8 KB, per-wave 16-row slices
  const int t = threadIdx.x;
  const int lane = t & 63, w = t >> 6;           // w = 0..7
  const int quad = lane >> 4, l16 = lane & 15;
  const int id = blockIdx.x;
  const int qt = id >> 6;                         // 0..15
  const int bh = ((id & 7) << 3) | ((id >> 3) & 7);   // XCD-clustered heads
  const long hoff = (long)bh * NSEQ * CDIM;
  const ushort_t* qp  = q  + hoff + (long)qt * 128 * CDIM;
  const ushort_t* kp  = k  + hoff;
  const ushort_t* vtp = vt + hoff;     // [64][2048]

  // Q frags (pre-scaled), loaded once: B operand, Q[qrow=w*16+l16][k]
  short8 qf[2];
#pragma unroll
  for (int kb = 0; kb < 2; ++kb)
    qf[kb] = *reinterpret_cast<const short8*>(
        qp + (w * 16 + l16) * 64 + kb * 32 + quad * 8);

  float4v O[4];   // [c-tile]
  float rs = 0.f;
#pragma unroll
  for (int ct = 0; ct < 4; ++ct)
#pragma unroll
    for (int r = 0; r < 4; ++r) O[ct][r] = 0.f;

  // staging constants (per lane); waves 0-3 stage K, waves 4-7 stage Vt
  const int ws = w & 3;
  const bool isK = (w < 4);
  const int krow = ws * 8 + (lane >> 3);         // K: 8 rows/wave
  const int kchk = (lane & 7) ^ (lane >> 3);     // ^ (row & 7)
  const int kdst = ws * 8 * 64;                  // u16
  const int vrow = ws * 16 + (lane >> 2);        // V: 16 c-rows/wave
  const int vchk = (lane & 3) ^ ((lane >> 3) & 3);  // ^ ((row>>1) & 3)
  const int vdst = ws * 16 * 32;                 // u16
  const int pswz = (l16 >> 1) & 3;               // Ps/Vs read swizzle term

  // prologue: stage tile 0 into buffer 0
  if (isK) glds16(kp + (long)krow * 64 + kchk * 8, &Ks2[0][kdst]);
  else     glds16(vtp + (long)vrow * 2048 + vchk * 8, &Vs2[0][vdst]);

  for (int tile = 0; tile < NSEQ / 32; ++tile) {
    const int cur = tile & 1;
    __syncthreads();   // implicit vmcnt(0): buf[cur] ready; buf[1-cur] free
    if (tile < NSEQ / 32 - 1) {
      const long nxt = tile + 1;
      if (isK) glds16(kp + (nxt * 32 + krow) * 64 + kchk * 8, &Ks2[1 - cur][kdst]);
      else     glds16(vtp + (long)vrow * 2048 + nxt * 32 + vchk * 8, &Vs2[1 - cur][vdst]);
    }

    // S^T = K Q^T  (2 kv-tiles x 1 q-tile of 16x16 per wave)
    float4v s[2];
#pragma unroll
    for (int nt = 0; nt < 2; ++nt)
#pragma unroll
      for (int r = 0; r < 4; ++r) s[nt][r] = 0.f;

#pragma unroll
    for (int kb = 0; kb < 2; ++kb) {
      short8 kf[2];   // A: K[kv=nt*16+l16][k=kb*32+quad*8+j]
#pragma unroll
      for (int nt = 0; nt < 2; ++nt)
        kf[nt] = *reinterpret_cast<const short8*>(
            &Ks2[cur][(nt * 16 + l16) * 64 + (((kb * 4 + quad) ^ (l16 & 7)) * 8)]);
#pragma unroll
      for (int nt = 0; nt < 2; ++nt)
        s[nt] = __builtin_amdgcn_mfma_f32_16x16x32_bf16(
            kf[nt], qf[kb], s[nt], 0, 0, 0);
    }

    // p = exp2(s'); lane-private partial sums; b64 pack into Ps[qrow][kv]
#pragma unroll
    for (int nt = 0; nt < 2; ++nt) {
      const float p0 = __builtin_amdgcn_exp2f(s[nt][0]);
      const float p1 = __builtin_amdgcn_exp2f(s[nt][1]);
      const float p2 = __builtin_amdgcn_exp2f(s[nt][2]);
      const float p3 = __builtin_amdgcn_exp2f(s[nt][3]);
      rs += (p0 + p1) + (p2 + p3);
      uint2 pk;
      pk.x = cvtpk(p0, p1);
      pk.y = cvtpk(p2, p3);
      *reinterpret_cast<uint2*>(
          &Ps[(w * 16 + l16) * 32 +
              (((nt * 2 + (quad >> 1)) ^ pswz) * 8) + (quad & 1) * 4]) = pk;
    }

    // O^T += Vt P^T  (wave-private Ps slice -> no barrier; k-depth = 32)
    {
      short8 pf, vf[4];
      pf = *reinterpret_cast<const short8*>(
          &Ps[(w * 16 + l16) * 32 + ((quad ^ pswz) * 8)]);
#pragma unroll
      for (int ct = 0; ct < 4; ++ct)
        vf[ct] = *reinterpret_cast<const short8*>(
            &Vs2[cur][(ct * 16 + l16) * 32 + ((quad ^ pswz) * 8)]);
#pragma unroll
      for (int ct = 0; ct < 4; ++ct)
        O[ct] = __builtin_amdgcn_mfma_f32_16x16x32_bf16(
            vf[ct], pf, O[ct], 0, 0, 0);
    }
  }

  // epilogue: quad-reduce row sum, normalize, head-mix shuffle, float4 out
  // final[b, h2, n, h*8+c2] = out_head[b, h, n, h2*8+c2]
  const int bi = bh >> 3, h = bh & 7;
  float l = rs;
  l += __shfl_xor(l, 16, 64);
  l += __shfl_xor(l, 32, 64);
  const float inv = 1.f / l;
#pragma unroll
  for (int ct = 0; ct < 4; ++ct) {
    const int n = qt * 128 + w * 16 + l16;
    const int h2 = ct * 2 + (quad >> 1);          // (ct*16+quad*4)>>3
    const int c2b = (quad & 1) * 4;
    float4 v4;
    v4.x = O[ct][0] * inv; v4.y = O[ct][1] * inv;
    v4.z = O[ct][2] * inv; v4.w = O[ct][3] * inv;
    *reinterpret_cast<float4*>(
        &out[(((long)(bi * 8 + h2)) * NSEQ + n) * 64 + h * 8 + c2b]) = v4;
  }
}

extern "C" void kernel_launch(void* const* d_in, const int* in_sizes, int n_in,
                              void* d_out, int out_size, void* d_ws, size_t ws_size,
                              hipStream_t stream) {
  (void)in_sizes; (void)n_in; (void)out_size; (void)ws_size;
  const float* x = (const float*)d_in[0];   // [8,8,2048,64] fp32
  const float* w = (const float*)d_in[1];   // [192,64] fp32
  float* out = (float*)d_out;               // [8,8,2048,64] fp32

  // workspace: Q(scaled),K natural + Vt transposed, bf16 bits, 16.78 MB each
  ushort_t* qws  = (ushort_t*)d_ws;
  ushort_t* kws  = qws + (size_t)BH * NSEQ * CDIM;
  ushort_t* vtws = kws + (size_t)BH * NSEQ * CDIM;

  qkv_proj_mfma<<<(BH * NSEQ) / 128, 256, 0, stream>>>(x, w, qws, kws, vtws);
  flash_attn_mfma<<<1024, 512, 0, stream>>>(qws, kws, vtws, out);
}

// Round 8
// 166.128 us; speedup vs baseline: 1.0476x; 1.0476x over previous
//
#include <hip/hip_runtime.h>
#include <math.h>

// Problem constants (B=8, H=8, N=2048, C=64). fp32 inputs/outputs.
// Q staged in d_ws as bf16 PRE-SCALED by C^-0.5 * log2(e) (flash uses exp2 =
// bare v_exp_f32). K natural [head][n][c]; V transposed Vt[head][c][n].
// Round 16:
//  - flash: R4 structure verbatim (TK=32, tm=2, grid 512; 85.7 us verified)
//    + s_setprio(1/0) around MFMA bursts (T5 hint, no correctness surface).
//  - proj: W converted once by w_prep into pre-swizzled bf16 image in the
//    TAIL OF THE OUT BUFFER (in-bounds; stream-ordered: w_prep writes ->
//    proj reads -> flash overwrites). Proj stages W via 6 glds16; MFMA
//    reads undo the XOR. Gather epilogue unchanged (verified R4).
//    NOTE: R5/R6 showed the old 0.118 failure was TK=64, NOT wimg; R3's
//    NaN was the ws-tail OOB. This is wimg's first clean test.
#define BH    64
#define NSEQ  2048
#define CDIM  64

typedef unsigned short ushort_t;
typedef __attribute__((ext_vector_type(8))) short short8;    // 8 bf16 (4 VGPR)
typedef __attribute__((ext_vector_type(4))) float float4v;   // mfma C/D

// fp32 -> bf16 bits, round-to-nearest-even
__device__ __forceinline__ ushort_t f32_to_bf16_rne(float x) {
  unsigned int u = __float_as_uint(x);
  u += 0x7fffu + ((u >> 16) & 1u);
  return (ushort_t)(u >> 16);
}

// pack 2 f32 -> 2 bf16 in a u32, single HW instruction (RNE)
__device__ __forceinline__ unsigned int cvtpk(float a, float b) {
  unsigned int r;
  asm("v_cvt_pk_bf16_f32 %0, %1, %2" : "=v"(r) : "v"(a), "v"(b));
  return r;
}

// async global->LDS, 16B per lane; LDS dest = wave-uniform base + lane*16
__device__ __forceinline__ void glds16(const ushort_t* g, ushort_t* l) {
  __builtin_amdgcn_global_load_lds(
      (const __attribute__((address_space(1))) void*)g,
      (__attribute__((address_space(3))) void*)l, 16, 0, 0);
}

// ---------------- W prep: fp32 [192][64] -> bf16 swizzled image -----------
// wimg[d*64 + ((ch ^ (d&7))*8) + j] = bf16(W[d][ch*8+j] * (d<64 ? s : 1)).
// Copied verbatim into proj's LDS by glds16; MFMA reads undo the XOR.
__global__ __launch_bounds__(256) void w_prep(
    const float* __restrict__ w, ushort_t* __restrict__ wimg) {
  const int t = threadIdx.x;
#pragma unroll
  for (int i = 0; i < 6; ++i) {
    const int idx = i * 256 + t;          // chunk index in [0,1536)
    const int d = idx >> 3, ch = idx & 7;
    const float sc = (d < 64) ? 0.1803368801111244f : 1.0f;  // 0.125*log2(e)
    const float4 f0 = *reinterpret_cast<const float4*>(w + d * 64 + ch * 8);
    const float4 f1 = *reinterpret_cast<const float4*>(w + d * 64 + ch * 8 + 4);
    uint4 pk4;
    pk4.x = cvtpk(f0.x * sc, f0.y * sc);
    pk4.y = cvtpk(f0.z * sc, f0.w * sc);
    pk4.z = cvtpk(f1.x * sc, f1.y * sc);
    pk4.w = cvtpk(f1.z * sc, f1.w * sc);
    *reinterpret_cast<uint4*>(wimg + d * 64 + ((ch ^ (d & 7)) * 8)) = pk4;
  }
}

// ---------------- QKV projection (MFMA, LDS-gathered coalesced stores) ----
// qkv[row, d] = sum_c x[row, c] * W[d, c];  d<64 -> Q (pre-scaled), <128 ->
// K, else V.  Q/K: acc = mfma(wf, xf) -> D[d][row]; V: acc = mfma(xf, wf) ->
// D[row][c] (free transpose for Vt).  W staged via glds16 from wimg (zero
// VALU).  Epilogue: pack accs into swizzled LDS (overlaid on Wb), read back
// linearly, store coalesced uint4.
__global__ __launch_bounds__(256) void qkv_proj_mfma(
    const float* __restrict__ x, const ushort_t* __restrict__ wimg,
    ushort_t* __restrict__ q, ushort_t* __restrict__ k,
    ushort_t* __restrict__ vt) {
  __shared__ ushort_t Wb[192 * 64];   // 24576 B swizzled W; reused as gather
  ushort_t* Sg = Wb;                  // overlay (16384 B needed)
  const int t = threadIdx.x;
  const int lane = t & 63, wv = t >> 6;
  const int quad = lane >> 4, l16 = lane & 15;
  const long rowbase = (long)blockIdx.x * 128;
  const int head  = (int)(rowbase >> 11);
  const int nbase = (int)(rowbase & 2047);

  // stage W image: 1536 chunks of 16B via glds16 (identity-linear copy)
#pragma unroll
  for (int i = 0; i < 6; ++i)
    glds16(wimg + (size_t)(i * 256 + t) * 8, &Wb[(i * 256 + wv * 64) * 8]);

  // A/B x-frags: x rows, converted to bf16 (overlaps glds16 flight)
  short8 xf[2][2];
#pragma unroll
  for (int tm = 0; tm < 2; ++tm)
#pragma unroll
    for (int kb = 0; kb < 2; ++kb) {
      const float* xp = x + (rowbase + wv * 32 + tm * 16 + l16) * 64 + kb * 32 + quad * 8;
      const float4 f0 = *reinterpret_cast<const float4*>(xp);
      const float4 f1 = *reinterpret_cast<const float4*>(xp + 4);
      ushort_t tmp[8] __attribute__((aligned(16)));
      tmp[0] = f32_to_bf16_rne(f0.x); tmp[1] = f32_to_bf16_rne(f0.y);
      tmp[2] = f32_to_bf16_rne(f0.z); tmp[3] = f32_to_bf16_rne(f0.w);
      tmp[4] = f32_to_bf16_rne(f1.x); tmp[5] = f32_to_bf16_rne(f1.y);
      tmp[6] = f32_to_bf16_rne(f1.z); tmp[7] = f32_to_bf16_rne(f1.w);
      xf[tm][kb] = *reinterpret_cast<const short8*>(tmp);
    }
  __syncthreads();   // implicit vmcnt(0): W image staged

  float4v aqk[8][2];   // [d-tile][x-tile], swapped: D[d][row]
  float4v av[2][4];    // [x-tile][d-tile], normal: D[row][c]
#pragma unroll
  for (int nt = 0; nt < 8; ++nt)
#pragma unroll
    for (int tm = 0; tm < 2; ++tm)
#pragma unroll
      for (int r = 0; r < 4; ++r) aqk[nt][tm][r] = 0.f;
#pragma unroll
  for (int tm = 0; tm < 2; ++tm)
#pragma unroll
    for (int nt = 0; nt < 4; ++nt)
#pragma unroll
      for (int r = 0; r < 4; ++r) av[tm][nt][r] = 0.f;

#pragma unroll
  for (int kb = 0; kb < 2; ++kb) {
#pragma unroll
    for (int nt = 0; nt < 8; ++nt) {
      const int r = nt * 16 + l16;
      const short8 wf = *reinterpret_cast<const short8*>(
          &Wb[r * 64 + (((kb * 4 + quad) ^ (r & 7)) * 8)]);
      aqk[nt][0] = __builtin_amdgcn_mfma_f32_16x16x32_bf16(wf, xf[0][kb], aqk[nt][0], 0, 0, 0);
      aqk[nt][1] = __builtin_amdgcn_mfma_f32_16x16x32_bf16(wf, xf[1][kb], aqk[nt][1], 0, 0, 0);
    }
#pragma unroll
    for (int nt = 0; nt < 4; ++nt) {
      const int r = 128 + nt * 16 + l16;
      const short8 wfv = *reinterpret_cast<const short8*>(
          &Wb[r * 64 + (((kb * 4 + quad) ^ (r & 7)) * 8)]);
      av[0][nt] = __builtin_amdgcn_mfma_f32_16x16x32_bf16(xf[0][kb], wfv, av[0][nt], 0, 0, 0);
      av[1][nt] = __builtin_amdgcn_mfma_f32_16x16x32_bf16(xf[1][kb], wfv, av[1][nt], 0, 0, 0);
    }
  }

  __syncthreads();   // all MFMA reads of Wb done -> safe to reuse as Sg

  // ---- Q section: gather into Sg[row][d] (chunk ^= row&7), store coalesced
#pragma unroll
  for (int tm = 0; tm < 2; ++tm) {
    const int row = wv * 32 + tm * 16 + l16;
#pragma unroll
    for (int nt = 0; nt < 4; ++nt) {
      const int dchunk = nt * 2 + (quad >> 1);
      uint2 pk;
      pk.x = cvtpk(aqk[nt][tm][0], aqk[nt][tm][1]);
      pk.y = cvtpk(aqk[nt][tm][2], aqk[nt][tm][3]);
      *reinterpret_cast<uint2*>(
          &Sg[row * 64 + ((dchunk ^ (row & 7)) * 8) + (quad & 1) * 4]) = pk;
    }
  }
  __syncthreads();
#pragma unroll
  for (int i = 0; i < 4; ++i) {
    const int g = i * 256 + t;           // 1024 chunks = 128 rows x 8
    const int row = g >> 3, ch = g & 7;
    const uint4 v = *reinterpret_cast<const uint4*>(
        &Sg[row * 64 + ((ch ^ (row & 7)) * 8)]);
    *reinterpret_cast<uint4*>(q + (rowbase + row) * 64 + ch * 8) = v;
  }
  __syncthreads();

  // ---- K section (reuse Sg)
#pragma unroll
  for (int tm = 0; tm < 2; ++tm) {
    const int row = wv * 32 + tm * 16 + l16;
#pragma unroll
    for (int nt = 4; nt < 8; ++nt) {
      const int dchunk = (nt - 4) * 2 + (quad >> 1);
      uint2 pk;
      pk.x = cvtpk(aqk[nt][tm][0], aqk[nt][tm][1]);
      pk.y = cvtpk(aqk[nt][tm][2], aqk[nt][tm][3]);
      *reinterpret_cast<uint2*>(
          &Sg[row * 64 + ((dchunk ^ (row & 7)) * 8) + (quad & 1) * 4]) = pk;
    }
  }
  __syncthreads();
#pragma unroll
  for (int i = 0; i < 4; ++i) {
    const int g = i * 256 + t;
    const int row = g >> 3, ch = g & 7;
    const uint4 v = *reinterpret_cast<const uint4*>(
        &Sg[row * 64 + ((ch ^ (row & 7)) * 8)]);
    *reinterpret_cast<uint4*>(k + (rowbase + row) * 64 + ch * 8) = v;
  }
  __syncthreads();

  // ---- V section: Sg as [64][128] (Sv[c][n_local], chunk ^= c&15)
#pragma unroll
  for (int tm = 0; tm < 2; ++tm)
#pragma unroll
    for (int nt = 0; nt < 4; ++nt) {
      const int c = nt * 16 + l16;
      const int nchunk = wv * 4 + tm * 2 + (quad >> 1);
      uint2 pk;
      pk.x = cvtpk(av[tm][nt][0], av[tm][nt][1]);
      pk.y = cvtpk(av[tm][nt][2], av[tm][nt][3]);
      *reinterpret_cast<uint2*>(
          &Sg[c * 128 + ((nchunk ^ (c & 15)) * 8) + (quad & 1) * 4]) = pk;
    }
  __syncthreads();
#pragma unroll
  for (int i = 0; i < 4; ++i) {
    const int g = i * 256 + t;           // 1024 chunks = 64 c-rows x 16
    const int c = g >> 4, ch = g & 15;
    const uint4 v = *reinterpret_cast<const uint4*>(
        &Sg[c * 128 + ((ch ^ (c & 15)) * 8)]);
    *reinterpret_cast<uint4*>(vt + (long)head * (64 * 2048) + (long)c * 2048 +
                              nbase + ch * 8) = v;
  }
}

// ---------------- MFMA flash attention (transposed dataflow, TQ=256) --------
// R4 structure verbatim (verified twice) + s_setprio around MFMA bursts.
// block: 512 threads = 8 waves, 32 q-rows per wave (tm=2). TK=32. grid 512
// (2 blocks/CU), XCD swizzle: bh = (id&7)*8 + (id>>3)&7, qt = id>>6.
// LDS (all XOR-swizzled, chunk = 8 u16 = 16B):
//   Ks2[2][32*64]: K tile [kv][c],  chunk' = chunk ^ (row&7)      (8 chunks/row)
//   Vs2[2][64*32]: Vt tile [c][kv], chunk' = chunk ^ ((row>>1)&3) (4 chunks/row)
//   Ps  [256*32]:  P [qrow][kv],    chunk' = chunk ^ ((row>>1)&3)
// Staging split: waves 0-3 stage K (8 rows each), waves 4-7 stage Vt
// (16 c-rows each) -- one glds16 per thread per tile.
// S^T = mfma(kf, qf): reg r = S[qrow=tm*16+l16][kv=nt*16+quad*4+r] -> b64 pack.
// O^T = mfma(vf, pf): reg r = O[qrow=tm*16+l16][c=ct*16+quad*4+r] -> float4 out.
__global__ __launch_bounds__(512, 4) void flash_attn_mfma(
    const ushort_t* __restrict__ q, const ushort_t* __restrict__ k,
    const ushort_t* __restrict__ vt, float* __restrict__ out) {
  __shared__ ushort_t Ks2[2][32 * 64];  // 8 KB
  __shared__ ushort_t Vs2[2][64 * 32];  // 8 KB
  __shared__ ushort_t Ps[256 * 32];     // 16 KB, per-wave 32-row slices
  const int t = threadIdx.x;
  const int lane = t & 63, w = t >> 6;           // w = 0..7
  const int quad = lane >> 4, l16 = lane & 15;
  const int id = blockIdx.x;
  const int qt = id >> 6;
  const int bh = ((id & 7) << 3) | ((id >> 3) & 7);   // XCD-clustered heads
  const long hoff = (long)bh * NSEQ * CDIM;
  const ushort_t* qp  = q  + hoff + (long)qt * 256 * CDIM;
  const ushort_t* kp  = k  + hoff;
  const ushort_t* vtp = vt + hoff;     // [64][2048]

  // Q frags (pre-scaled), loaded once: B operand, Q[qrow=w*32+tm*16+l16][k]
  short8 qf[2][2];
#pragma unroll
  for (int tm = 0; tm < 2; ++tm)
#pragma unroll
    for (int kb = 0; kb < 2; ++kb)
      qf[tm][kb] = *reinterpret_cast<const short8*>(
          qp + (w * 32 + tm * 16 + l16) * 64 + kb * 32 + quad * 8);

  float4v O[4][2];   // [c-tile][q-tile]
  float rs[2];
  rs[0] = 0.f; rs[1] = 0.f;
#pragma unroll
  for (int ct = 0; ct < 4; ++ct)
#pragma unroll
    for (int tm = 0; tm < 2; ++tm)
#pragma unroll
      for (int r = 0; r < 4; ++r) O[ct][tm][r] = 0.f;

  // staging constants (per lane); waves 0-3 stage K, waves 4-7 stage Vt
  const int ws = w & 3;
  const bool isK = (w < 4);
  const int krow = ws * 8 + (lane >> 3);         // K: 8 rows/wave
  const int kchk = (lane & 7) ^ (lane >> 3);     // ^ (row & 7)
  const int kdst = ws * 8 * 64;                  // u16
  const int vrow = ws * 16 + (lane >> 2);        // V: 16 c-rows/wave
  const int vchk = (lane & 3) ^ ((lane >> 3) & 3);  // ^ ((row>>1) & 3)
  const int vdst = ws * 16 * 32;                 // u16
  const int pswz = (l16 >> 1) & 3;               // Ps/Vs read swizzle term

  // prologue: stage tile 0 into buffer 0
  if (isK) glds16(kp + (long)krow * 64 + kchk * 8, &Ks2[0][kdst]);
  else     glds16(vtp + (long)vrow * 2048 + vchk * 8, &Vs2[0][vdst]);

  for (int tile = 0; tile < NSEQ / 32; ++tile) {
    const int cur = tile & 1;
    __syncthreads();   // implicit vmcnt(0): buf[cur] ready; buf[1-cur] free
    if (tile < NSEQ / 32 - 1) {
      const long nxt = tile + 1;
      if (isK) glds16(kp + (nxt * 32 + krow) * 64 + kchk * 8, &Ks2[1 - cur][kdst]);
      else     glds16(vtp + (long)vrow * 2048 + nxt * 32 + vchk * 8, &Vs2[1 - cur][vdst]);
    }

    // S^T = K Q^T  (2 kv-tiles x 2 q-tiles of 16x16 per wave)
    float4v s[2][2];
#pragma unroll
    for (int nt = 0; nt < 2; ++nt)
#pragma unroll
      for (int tm = 0; tm < 2; ++tm)
#pragma unroll
        for (int r = 0; r < 4; ++r) s[nt][tm][r] = 0.f;

#pragma unroll
    for (int kb = 0; kb < 2; ++kb) {
      short8 kf[2];   // A: K[kv=nt*16+l16][k=kb*32+quad*8+j]
#pragma unroll
      for (int nt = 0; nt < 2; ++nt)
        kf[nt] = *reinterpret_cast<const short8*>(
            &Ks2[cur][(nt * 16 + l16) * 64 + (((kb * 4 + quad) ^ (l16 & 7)) * 8)]);
      __builtin_amdgcn_s_setprio(1);
#pragma unroll
      for (int nt = 0; nt < 2; ++nt)
#pragma unroll
        for (int tm = 0; tm < 2; ++tm)
          s[nt][tm] = __builtin_amdgcn_mfma_f32_16x16x32_bf16(
              kf[nt], qf[tm][kb], s[nt][tm], 0, 0, 0);
      __builtin_amdgcn_s_setprio(0);
    }

    // p = exp2(s'); lane-private partial sums; b64 pack into Ps[qrow][kv]
#pragma unroll
    for (int tm = 0; tm < 2; ++tm)
#pragma unroll
      for (int nt = 0; nt < 2; ++nt) {
        const float p0 = __builtin_amdgcn_exp2f(s[nt][tm][0]);
        const float p1 = __builtin_amdgcn_exp2f(s[nt][tm][1]);
        const float p2 = __builtin_amdgcn_exp2f(s[nt][tm][2]);
        const float p3 = __builtin_amdgcn_exp2f(s[nt][tm][3]);
        rs[tm] += (p0 + p1) + (p2 + p3);
        uint2 pk;
        pk.x = cvtpk(p0, p1);
        pk.y = cvtpk(p2, p3);
        *reinterpret_cast<uint2*>(
            &Ps[(w * 32 + tm * 16 + l16) * 32 +
                (((nt * 2 + (quad >> 1)) ^ pswz) * 8) + (quad & 1) * 4]) = pk;
      }

    // O^T += Vt P^T  (wave-private Ps slice -> no barrier; k-depth = 32)
    {
      short8 pf[2], vf[4];
#pragma unroll
      for (int tm = 0; tm < 2; ++tm)
        pf[tm] = *reinterpret_cast<const short8*>(
            &Ps[(w * 32 + tm * 16 + l16) * 32 + ((quad ^ pswz) * 8)]);
#pragma unroll
      for (int ct = 0; ct < 4; ++ct)
        vf[ct] = *reinterpret_cast<const short8*>(
            &Vs2[cur][(ct * 16 + l16) * 32 + ((quad ^ pswz) * 8)]);
      __builtin_amdgcn_s_setprio(1);
#pragma unroll
      for (int ct = 0; ct < 4; ++ct)
#pragma unroll
        for (int tm = 0; tm < 2; ++tm)
          O[ct][tm] = __builtin_amdgcn_mfma_f32_16x16x32_bf16(
              vf[ct], pf[tm], O[ct][tm], 0, 0, 0);
      __builtin_amdgcn_s_setprio(0);
    }
  }

  // epilogue: quad-reduce row sums, normalize, head-mix shuffle, float4 out
  // final[b, h2, n, h*8+c2] = out_head[b, h, n, h2*8+c2]
  const int bi = bh >> 3, h = bh & 7;
  float inv[2];
#pragma unroll
  for (int tm = 0; tm < 2; ++tm) {
    float l = rs[tm];
    l += __shfl_xor(l, 16, 64);
    l += __shfl_xor(l, 32, 64);
    inv[tm] = 1.f / l;
  }
#pragma unroll
  for (int ct = 0; ct < 4; ++ct)
#pragma unroll
    for (int tm = 0; tm < 2; ++tm) {
      const int n = qt * 256 + w * 32 + tm * 16 + l16;
      const int h2 = ct * 2 + (quad >> 1);          // (ct*16+quad*4)>>3
      const int c2b = (quad & 1) * 4;
      float4 v4;
      v4.x = O[ct][tm][0] * inv[tm]; v4.y = O[ct][tm][1] * inv[tm];
      v4.z = O[ct][tm][2] * inv[tm]; v4.w = O[ct][tm][3] * inv[tm];
      *reinterpret_cast<float4*>(
          &out[(((long)(bi * 8 + h2)) * NSEQ + n) * 64 + h * 8 + c2b]) = v4;
    }
}

extern "C" void kernel_launch(void* const* d_in, const int* in_sizes, int n_in,
                              void* d_out, int out_size, void* d_ws, size_t ws_size,
                              hipStream_t stream) {
  (void)in_sizes; (void)n_in; (void)out_size; (void)ws_size;
  const float* x = (const float*)d_in[0];   // [8,8,2048,64] fp32
  const float* w = (const float*)d_in[1];   // [192,64] fp32
  float* out = (float*)d_out;               // [8,8,2048,64] fp32

  // workspace: Q(scaled),K natural + Vt transposed, bf16 bits, 16.78 MB each
  ushort_t* qws  = (ushort_t*)d_ws;
  ushort_t* kws  = qws + (size_t)BH * NSEQ * CDIM;
  ushort_t* vtws = kws + (size_t)BH * NSEQ * CDIM;

  // W image in the TAIL of out (24,576 B = 6144 floats, in-bounds):
  // w_prep writes it, proj reads it, flash fully overwrites out afterward.
  ushort_t* wimg = (ushort_t*)(out + (size_t)8 * 8 * 2048 * 64 - 6144);

  w_prep<<<1, 256, 0, stream>>>(w, wimg);
  qkv_proj_mfma<<<(BH * NSEQ) / 128, 256, 0, stream>>>(x, wimg, qws, kws, vtws);
  flash_attn_mfma<<<512, 512, 0, stream>>>(qws, kws, vtws, out);
}